// Round 8
// baseline (432.986 us; speedup 1.0000x reference)
//
#include <hip/hip_runtime.h>

#define N_GRAPHS 64
#define IN_FEATS 64
#define HIDDEN 32

#define NB 512        // dst-range buckets
#define PCH 2048      // edges per partition block
#define GCH 256       // nodes per gsum chunk (R1-proven)
#define HISTB 512     // hist-role blocks in fused launch

// ---------------- K0: init ----------------
// graph bounds, ge zero, gcount zero, M = W1@W2@W3 [64,2], c1 = b1@W2@W3, c2 = b2@W3
__global__ __launch_bounds__(256) void k_init(const int* __restrict__ gids, int n,
                                              int* __restrict__ gstart,
                                              float* __restrict__ ge,
                                              int* __restrict__ gcount,
                                              int* __restrict__ done,
                                              const float* __restrict__ W1,
                                              const float* __restrict__ b1,
                                              const float* __restrict__ W2,
                                              const float* __restrict__ b2,
                                              const float* __restrict__ W3,
                                              float* __restrict__ Mg,
                                              float* __restrict__ cc) {
    __shared__ float w23[HIDDEN * 2];
    int tid = threadIdx.x;
    for (int i = tid; i < N_GRAPHS * IN_FEATS; i += 256) ge[i] = 0.f;
    for (int i = tid; i < NB; i += 256) gcount[i] = 0;
    if (tid < 2) done[tid] = 0;
    if (tid <= N_GRAPHS) {
        int g = tid;
        int lo = 0, hi = n;
        while (lo < hi) {
            int mid = (lo + hi) >> 1;
            if (gids[mid] < g) lo = mid + 1; else hi = mid;
        }
        gstart[g] = lo;
    }
    // W23 = W2 @ W3  [32,2]
    if (tid < HIDDEN * 2) {
        int r = tid >> 1, o = tid & 1;
        float s = 0.f;
        for (int k = 0; k < HIDDEN; k++) s += W2[r * HIDDEN + k] * W3[k * 2 + o];
        w23[tid] = s;
    }
    __syncthreads();
    // M = W1 @ W23  [64,2]
    if (tid < IN_FEATS * 2) {
        int r = tid >> 1, o = tid & 1;
        float s = 0.f;
        for (int k = 0; k < HIDDEN; k++) s += W1[r * HIDDEN + k] * w23[k * 2 + o];
        Mg[tid] = s;
    }
    // c1 = b1 @ W23 ; c2 = b2 @ W3
    if (tid < 2) {
        float s1 = 0.f, s2 = 0.f;
        for (int k = 0; k < HIDDEN; k++) {
            s1 += b1[k] * w23[k * 2 + tid];
            s2 += b2[k] * W3[k * 2 + tid];
        }
        cc[tid] = 0.f;       // c for hop 1 (none)
        cc[2 + tid] = s1;    // c1 for hop 2
        cc[4 + tid] = s2;    // c2 for hop 3
    }
}

// ---------------- K1 (fused): {gsum + y0, R1-PROVEN body} ∥ {hist} ----------------
__global__ __launch_bounds__(256) void k_gsum_y0h(const float* __restrict__ nf,
                                                  const int* __restrict__ gids,
                                                  const int* __restrict__ gstart,
                                                  float* __restrict__ ge, int N,
                                                  int gsBlocks,
                                                  const float* __restrict__ Mg,
                                                  float* __restrict__ y0,
                                                  const int* __restrict__ dst,
                                                  int* __restrict__ gcount,
                                                  int E, int nb_sz) {
    int tid = threadIdx.x;

    if (blockIdx.x >= gsBlocks) {
        // ---- hist role ----
        __shared__ int lc[NB];
        for (int k = tid; k < NB; k += 256) lc[k] = 0;
        __syncthreads();
        int bid = blockIdx.x - gsBlocks;
        int stride = HISTB * 256;
        for (int i = bid * 256 + tid; i < E; i += stride)
            atomicAdd(&lc[dst[i] / nb_sz], 1);
        __syncthreads();
        for (int k = tid; k < NB; k += 256)
            if (lc[k]) atomicAdd(&gcount[k], lc[k]);
        return;
    }

    // ---- gsum + y0 role (R1-proven body; do not re-roll) ----
    int c0 = blockIdx.x * GCH;
    int c1 = c0 + GCH; if (c1 > N) c1 = N;
    int ng = tid >> 4;
    int f4 = tid & 15;

    __shared__ float2 Ms[IN_FEATS];
    if (tid < IN_FEATS) Ms[tid] = reinterpret_cast<const float2*>(Mg)[tid];

    if (c0 < N) {
        int gfirst = gids[c0];
        int glast  = gids[c1 - 1];
        __shared__ float4 red[256];
        for (int g = gfirst; g <= glast; g++) {
            int s = gstart[g];     if (s < c0) s = c0;
            int e = gstart[g + 1]; if (e > c1) e = c1;
            float4 acc = make_float4(0.f, 0.f, 0.f, 0.f);
            for (int i = s + ng; i < e; i += 16) {
                float4 v = *reinterpret_cast<const float4*>(nf + (long long)i * IN_FEATS + f4 * 4);
                acc.x += v.x; acc.y += v.y; acc.z += v.z; acc.w += v.w;
            }
            red[tid] = acc;
            __syncthreads();
            for (int off = 8; off > 0; off >>= 1) {
                if (ng < off) {
                    float4 o = red[(ng + off) * 16 + f4];
                    float4 m = red[tid];
                    m.x += o.x; m.y += o.y; m.z += o.z; m.w += o.w;
                    red[tid] = m;
                }
                __syncthreads();
            }
            if (ng == 0 && e > s) {
                float4 m = red[f4];
                atomicAdd(&ge[g * IN_FEATS + f4 * 4 + 0], m.x);
                atomicAdd(&ge[g * IN_FEATS + f4 * 4 + 1], m.y);
                atomicAdd(&ge[g * IN_FEATS + f4 * 4 + 2], m.z);
                atomicAdd(&ge[g * IN_FEATS + f4 * 4 + 3], m.w);
            }
            __syncthreads();
        }
    }
    __syncthreads();

    // y0 pass: one row per thread, reads hit L1/L2 (chunk just streamed above)
    {
        int row = c0 + tid;
        if (row < c1) {
            const float4* r4 = reinterpret_cast<const float4*>(nf + (long long)row * IN_FEATS);
            float a0 = 0.f, a1 = 0.f;
            #pragma unroll
            for (int v = 0; v < IN_FEATS / 4; v++) {
                float4 q = r4[v];
                float2 m0 = Ms[4 * v + 0], m1 = Ms[4 * v + 1];
                float2 m2 = Ms[4 * v + 2], m3 = Ms[4 * v + 3];
                a0 += q.x * m0.x + q.y * m1.x + q.z * m2.x + q.w * m3.x;
                a1 += q.x * m0.y + q.y * m1.y + q.z * m2.y + q.w * m3.y;
            }
            reinterpret_cast<float2*>(y0)[row] = make_float2(a0, a1);
        }
    }
}

// ---------------- K2 (mega): partition + {pred + scan} (block 0) + {csr finalize} (last NB blocks) ----------------
// Sync plan: block0 pred+scan -> flag(done[0]); all blocks stage locally; non-0 blocks spin
// on flag before rbase/scatter; after scatter every block fences + bumps done[1]; the last
// NB blocks spin until done[1]==gridDim, acquire-fence, then build csr/ptr for one bucket
// each (pairs still L2-warm). Deadlock-safe: __launch_bounds__(256,4) + 22.5KB LDS ->
// >=4 blocks/CU -> 1024 >= 782 all co-resident.
__global__ __launch_bounds__(256, 4) void k_partition(const int* __restrict__ src,
                                                      const int* __restrict__ dst,
                                                      const int* __restrict__ gcount,
                                                      int* __restrict__ gcur,
                                                      int* __restrict__ gbase,
                                                      unsigned int* __restrict__ pairs,
                                                      int E, int nb_sz,
                                                      const float* __restrict__ ge,
                                                      const int* __restrict__ gstart,
                                                      const float* __restrict__ Wl,
                                                      const float* __restrict__ bl,
                                                      float* __restrict__ out,
                                                      int* __restrict__ flag,
                                                      int* __restrict__ done2,
                                                      int* __restrict__ csr,
                                                      int* __restrict__ ptr,
                                                      int N) {
    __shared__ unsigned int stage[PCH];
    __shared__ unsigned short sbk[PCH];
    __shared__ int sA[NB], sB[NB], ofs[NB + 1], cur[NB], rbase[NB];
    int tid = threadIdx.x;

    if (blockIdx.x == 0) {
        // ---- prediction ----
        if (tid < N_GRAPHS) {
            int g = tid;
            float cnt = (float)(gstart[g + 1] - gstart[g]);
            float inv = 1.f / fmaxf(cnt, 1.0f);
            float acc = 0.f;
            for (int k = 0; k < IN_FEATS; k++)
                acc += ge[g * IN_FEATS + k] * Wl[k];
            acc = acc * inv + bl[0];
            out[g] = 1.f / (1.f + expf(-acc));
        }
        // ---- exclusive scan of gcount -> gbase, gcur ----
        int c0 = gcount[tid], c1 = gcount[tid + 256];
        sA[tid] = c0; sA[tid + 256] = c1;
        __syncthreads();
        int* a = sA; int* bb = sB;
        for (int off = 1; off < NB; off <<= 1) {
            for (int k = tid; k < NB; k += 256) {
                int v = a[k];
                if (k >= off) v += a[k - off];
                bb[k] = v;
            }
            __syncthreads();
            int* t_ = a; a = bb; bb = t_;
        }
        int e0 = a[tid] - c0, e1 = a[tid + 256] - c1;
        gbase[tid] = e0;       gbase[tid + 256] = e1;
        gcur[tid] = e0;        gcur[tid + 256] = e1;
        if (tid == 0) gbase[NB] = E;
        __threadfence();
        __syncthreads();
        if (tid == 0) atomicExch(flag, 1);
        __syncthreads();
    }

    // ---- local staging (all blocks) ----
    int e0b = blockIdx.x * PCH;
    int m = E - e0b; if (m > PCH) m = PCH;

    for (int k = tid; k < NB; k += 256) sA[k] = 0;
    __syncthreads();
    for (int i = tid; i < m; i += 256)
        atomicAdd(&sA[dst[e0b + i] / nb_sz], 1);
    __syncthreads();
    int c0 = sA[tid], c1 = sA[tid + 256];
    int* a = sA; int* bb = sB;
    for (int off = 1; off < NB; off <<= 1) {
        for (int k = tid; k < NB; k += 256) {
            int v = a[k];
            if (k >= off) v += a[k - off];
            bb[k] = v;
        }
        __syncthreads();
        int* t_ = a; a = bb; bb = t_;
    }
    int x0 = a[tid] - c0, x1 = a[tid + 256] - c1;
    ofs[tid] = x0;       ofs[tid + 256] = x1;
    cur[tid] = x0;       cur[tid + 256] = x1;
    if (tid == 0) ofs[NB] = m;
    __syncthreads();
    for (int i = tid; i < m; i += 256) {
        int d = dst[e0b + i];
        int s = src[e0b + i];
        int b = d / nb_sz;
        int p = atomicAdd(&cur[b], 1);
        stage[p] = ((unsigned)s << 8) | (unsigned)(d - b * nb_sz);
        sbk[p] = (unsigned short)b;
    }
    __syncthreads();

    // ---- wait for scan (blocks != 0), then global rbase + scatter ----
    if (blockIdx.x != 0) {
        if (tid == 0) {
            while (atomicAdd(flag, 0) == 0) __builtin_amdgcn_s_sleep(16);
            __threadfence();
        }
        __syncthreads();
    }
    for (int k = tid; k < NB; k += 256) {
        int cnt = ofs[k + 1] - ofs[k];
        rbase[k] = cnt > 0 ? atomicAdd(&gcur[k], cnt) : 0;
    }
    __syncthreads();
    for (int i = tid; i < m; i += 256) {
        int b = sbk[i];
        pairs[rbase[b] + (i - ofs[b])] = stage[i];
    }

    // ---- signal scatter completion ----
    __threadfence();
    __syncthreads();
    if (tid == 0) atomicAdd(done2, 1);

    // ---- csr finalize: last NB blocks handle one bucket each ----
    int cb = blockIdx.x - ((int)gridDim.x - NB);
    if (cb < 0) return;
    if (tid == 0) {
        while (atomicAdd(done2, 0) < (int)gridDim.x) __builtin_amdgcn_s_sleep(16);
    }
    __syncthreads();
    __threadfence();   // acquire: invalidate stale cached pairs/gbase lines

    int n0 = cb * nb_sz;
    if (n0 >= N) return;
    int n1 = n0 + nb_sz; if (n1 > N) n1 = N;
    int nn = n1 - n0;

    // reuse sA (cnt), sB (scn), cur
    sA[tid] = 0;
    __syncthreads();
    int s = gbase[cb], e = gbase[cb + 1];
    for (int i = s + tid; i < e; i += 256)
        atomicAdd(&sA[pairs[i] & 0xFFu], 1);
    __syncthreads();
    int c = sA[tid];
    sB[tid] = c;
    __syncthreads();
    for (int off = 1; off < 256; off <<= 1) {
        int mine = sB[tid];
        int add = (tid >= off) ? sB[tid - off] : 0;
        __syncthreads();
        sB[tid] = mine + add;
        __syncthreads();
    }
    cur[tid] = sB[tid] - c;
    if (tid < nn) ptr[n0 + tid] = s + sB[tid];   // end offset
    __syncthreads();
    for (int i = s + tid; i < e; i += 256) {
        unsigned int p = pairs[i];
        int pos = atomicAdd(&cur[p & 0xFFu], 1);
        csr[s + pos] = (int)(p >> 8);
    }
}

// ---------------- hop gathers: 8 lanes per node (R1-proven) ----------------
__global__ __launch_bounds__(256) void k_gather8(const float* __restrict__ tin,
                                                 const int* __restrict__ csr,
                                                 const int* __restrict__ ptr,
                                                 const float* __restrict__ cadd,
                                                 float* __restrict__ tout, int n) {
    int t = blockIdx.x * 256 + threadIdx.x;
    int node = t >> 3;
    int lane = t & 7;
    if (node >= n) return;
    int start = node ? ptr[node - 1] : 0;
    int end = ptr[node];
    const float2* tin2 = reinterpret_cast<const float2*>(tin);
    float a0 = 0.f, a1 = 0.f;
    int j = start + lane;
    for (; j + 8 < end; j += 16) {
        int s0 = csr[j], s1 = csr[j + 8];
        float2 v0 = tin2[s0], v1 = tin2[s1];
        a0 += v0.x + v1.x;
        a1 += v0.y + v1.y;
    }
    if (j < end) {
        float2 v = tin2[csr[j]];
        a0 += v.x; a1 += v.y;
    }
    #pragma unroll
    for (int off = 4; off > 0; off >>= 1) {
        a0 += __shfl_xor(a0, off, 64);
        a1 += __shfl_xor(a1, off, 64);
    }
    if (lane == 0) {
        float deg = (float)(end - start);
        reinterpret_cast<float2*>(tout)[node] = make_float2(a0 + deg * cadd[0], a1 + deg * cadd[1]);
    }
}

// hop 3 fused with +b3, straight into d_out
__global__ __launch_bounds__(256) void k_gather8_out(const float* __restrict__ tin,
                                                     const int* __restrict__ csr,
                                                     const int* __restrict__ ptr,
                                                     const float* __restrict__ cadd,
                                                     const float* __restrict__ b3,
                                                     float* __restrict__ out, int n) {
    int t = blockIdx.x * 256 + threadIdx.x;
    int node = t >> 3;
    int lane = t & 7;
    if (node >= n) return;
    int start = node ? ptr[node - 1] : 0;
    int end = ptr[node];
    const float2* tin2 = reinterpret_cast<const float2*>(tin);
    float a0 = 0.f, a1 = 0.f;
    int j = start + lane;
    for (; j + 8 < end; j += 16) {
        int s0 = csr[j], s1 = csr[j + 8];
        float2 v0 = tin2[s0], v1 = tin2[s1];
        a0 += v0.x + v1.x;
        a1 += v0.y + v1.y;
    }
    if (j < end) {
        float2 v = tin2[csr[j]];
        a0 += v.x; a1 += v.y;
    }
    #pragma unroll
    for (int off = 4; off > 0; off >>= 1) {
        a0 += __shfl_xor(a0, off, 64);
        a1 += __shfl_xor(a1, off, 64);
    }
    if (lane == 0) {
        float deg = (float)(end - start);
        reinterpret_cast<float2*>(out)[node] =
            make_float2(a0 + deg * cadd[0] + b3[0], a1 + deg * cadd[1] + b3[1]);
    }
}

extern "C" void kernel_launch(void* const* d_in, const int* in_sizes, int n_in,
                              void* d_out, int out_size, void* d_ws, size_t ws_size,
                              hipStream_t stream) {
    const float* nf = (const float*)d_in[0];   // node_feats f32 [N,64]
    const float* W1 = (const float*)d_in[2];   // [64,32]
    const float* b1 = (const float*)d_in[3];   // [32]
    const float* W2 = (const float*)d_in[4];   // [32,32]
    const float* b2 = (const float*)d_in[5];   // [32]
    const float* W3 = (const float*)d_in[6];   // [32,2]
    const float* b3 = (const float*)d_in[7];   // [2]
    const float* Wl = (const float*)d_in[8];   // [64,1]
    const float* bl = (const float*)d_in[9];   // [1]
    const int* src  = (const int*)d_in[10];
    const int* dst  = (const int*)d_in[11];
    const int* gids = (const int*)d_in[12];

    const int N = in_sizes[0] / IN_FEATS;     // 100000
    const int E = in_sizes[10];               // 1600000
    const int nb_sz = (N + NB - 1) / NB;      // 196 (<=256 required for packing)

    float* out = (float*)d_out;

    // workspace: y0/t [N,2] ×2 ping-pong | pairs [E] | csr [E] | ptr [N] | small
    float* yA = (float*)d_ws;                 // [N,2]
    float* yB = yA + (size_t)N * 2;           // [N,2]
    unsigned int* pairs = (unsigned int*)(yB + (size_t)N * 2); // [E]
    int* csr     = (int*)(pairs + E);         // [E]
    int* ptr     = csr + E;                   // [N]
    int* gcount  = ptr + N;                   // [NB]
    int* gbase   = gcount + NB;               // [NB+1]
    int* gcur    = gbase + NB + 1;            // [NB]
    float* Mg    = (float*)(gcur + NB);       // [64,2]
    float* cc    = Mg + IN_FEATS * 2;         // [6]
    float* ge    = cc + 8;                    // [64,64]
    int* gstart  = (int*)(ge + N_GRAPHS * IN_FEATS); // [65]
    int* done    = gstart + N_GRAPHS + 1;     // [2]

    const int TB = 256;
    int gsBlocks = (N + GCH - 1) / GCH;       // 391
    int partBlocks = (E + PCH - 1) / PCH;     // 782
    int gathBlocks = ((N * 8) + TB - 1) / TB; // 3125

    // K0: bounds + zeros + folded weights
    k_init<<<1, TB, 0, stream>>>(gids, N, gstart, ge, gcount, done,
                                 W1, b1, W2, b2, W3, Mg, cc);

    // K1: fused {gsum + y0} ∥ {hist}
    k_gsum_y0h<<<gsBlocks + HISTB, TB, 0, stream>>>(nf, gids, gstart, ge, N, gsBlocks,
                                                    Mg, yA, dst, gcount, E, nb_sz);

    // K2: mega partition {pred+scan | stage | scatter | csr finalize}
    k_partition<<<partBlocks, TB, 0, stream>>>(src, dst, gcount, gcur, gbase, pairs,
                                               E, nb_sz, ge, gstart, Wl, bl, out,
                                               done + 0, done + 1, csr, ptr, N);

    // K3..K5: three 2-wide hops, 8 lanes/node edge-parallel
    k_gather8<<<gathBlocks, TB, 0, stream>>>(yA, csr, ptr, cc + 0, yB, N);       // hop1
    k_gather8<<<gathBlocks, TB, 0, stream>>>(yB, csr, ptr, cc + 2, yA, N);       // hop2 (+c1)
    k_gather8_out<<<gathBlocks, TB, 0, stream>>>(yA, csr, ptr, cc + 4, b3,
                                                 out + N_GRAPHS, N);             // hop3 (+c2,+b3)
}

// Round 9
// 281.304 us; speedup vs baseline: 1.5392x; 1.5392x over previous
//
#include <hip/hip_runtime.h>

#define N_GRAPHS 64
#define IN_FEATS 64
#define HIDDEN 32

#define NB 512        // dst-range buckets
#define PCH 2048      // edges per partition block
#define GCH 256       // nodes per gsum chunk (R1-proven)
#define HISTB 512     // hist-role blocks in fused launch

// ---------------- K0: init ----------------
// graph bounds, ge zero, gcount zero, M = W1@W2@W3 [64,2], c1 = b1@W2@W3, c2 = b2@W3
__global__ __launch_bounds__(256) void k_init(const int* __restrict__ gids, int n,
                                              int* __restrict__ gstart,
                                              float* __restrict__ ge,
                                              int* __restrict__ gcount,
                                              int* __restrict__ done,
                                              const float* __restrict__ W1,
                                              const float* __restrict__ b1,
                                              const float* __restrict__ W2,
                                              const float* __restrict__ b2,
                                              const float* __restrict__ W3,
                                              float* __restrict__ Mg,
                                              float* __restrict__ cc) {
    __shared__ float w23[HIDDEN * 2];
    int tid = threadIdx.x;
    for (int i = tid; i < N_GRAPHS * IN_FEATS; i += 256) ge[i] = 0.f;
    for (int i = tid; i < NB; i += 256) gcount[i] = 0;
    if (tid < 2) done[tid] = 0;
    if (tid <= N_GRAPHS) {
        int g = tid;
        int lo = 0, hi = n;
        while (lo < hi) {
            int mid = (lo + hi) >> 1;
            if (gids[mid] < g) lo = mid + 1; else hi = mid;
        }
        gstart[g] = lo;
    }
    // W23 = W2 @ W3  [32,2]
    if (tid < HIDDEN * 2) {
        int r = tid >> 1, o = tid & 1;
        float s = 0.f;
        for (int k = 0; k < HIDDEN; k++) s += W2[r * HIDDEN + k] * W3[k * 2 + o];
        w23[tid] = s;
    }
    __syncthreads();
    // M = W1 @ W23  [64,2]
    if (tid < IN_FEATS * 2) {
        int r = tid >> 1, o = tid & 1;
        float s = 0.f;
        for (int k = 0; k < HIDDEN; k++) s += W1[r * HIDDEN + k] * w23[k * 2 + o];
        Mg[tid] = s;
    }
    // c1 = b1 @ W23 ; c2 = b2 @ W3
    if (tid < 2) {
        float s1 = 0.f, s2 = 0.f;
        for (int k = 0; k < HIDDEN; k++) {
            s1 += b1[k] * w23[k * 2 + tid];
            s2 += b2[k] * W3[k * 2 + tid];
        }
        cc[tid] = 0.f;       // c for hop 1 (none)
        cc[2 + tid] = s1;    // c1 for hop 2
        cc[4 + tid] = s2;    // c2 for hop 3
    }
}

// ---------------- K1 (fused): {gsum + y0, R1-PROVEN body} ∥ {hist} ----------------
__global__ __launch_bounds__(256) void k_gsum_y0h(const float* __restrict__ nf,
                                                  const int* __restrict__ gids,
                                                  const int* __restrict__ gstart,
                                                  float* __restrict__ ge, int N,
                                                  int gsBlocks,
                                                  const float* __restrict__ Mg,
                                                  float* __restrict__ y0,
                                                  const int* __restrict__ dst,
                                                  int* __restrict__ gcount,
                                                  int E, int nb_sz) {
    int tid = threadIdx.x;

    if (blockIdx.x >= gsBlocks) {
        // ---- hist role ----
        __shared__ int lc[NB];
        for (int k = tid; k < NB; k += 256) lc[k] = 0;
        __syncthreads();
        int bid = blockIdx.x - gsBlocks;
        int stride = HISTB * 256;
        for (int i = bid * 256 + tid; i < E; i += stride)
            atomicAdd(&lc[dst[i] / nb_sz], 1);
        __syncthreads();
        for (int k = tid; k < NB; k += 256)
            if (lc[k]) atomicAdd(&gcount[k], lc[k]);
        return;
    }

    // ---- gsum + y0 role (R1-proven body; do not re-roll) ----
    int c0 = blockIdx.x * GCH;
    int c1 = c0 + GCH; if (c1 > N) c1 = N;
    int ng = tid >> 4;
    int f4 = tid & 15;

    __shared__ float2 Ms[IN_FEATS];
    if (tid < IN_FEATS) Ms[tid] = reinterpret_cast<const float2*>(Mg)[tid];

    if (c0 < N) {
        int gfirst = gids[c0];
        int glast  = gids[c1 - 1];
        __shared__ float4 red[256];
        for (int g = gfirst; g <= glast; g++) {
            int s = gstart[g];     if (s < c0) s = c0;
            int e = gstart[g + 1]; if (e > c1) e = c1;
            float4 acc = make_float4(0.f, 0.f, 0.f, 0.f);
            for (int i = s + ng; i < e; i += 16) {
                float4 v = *reinterpret_cast<const float4*>(nf + (long long)i * IN_FEATS + f4 * 4);
                acc.x += v.x; acc.y += v.y; acc.z += v.z; acc.w += v.w;
            }
            red[tid] = acc;
            __syncthreads();
            for (int off = 8; off > 0; off >>= 1) {
                if (ng < off) {
                    float4 o = red[(ng + off) * 16 + f4];
                    float4 m = red[tid];
                    m.x += o.x; m.y += o.y; m.z += o.z; m.w += o.w;
                    red[tid] = m;
                }
                __syncthreads();
            }
            if (ng == 0 && e > s) {
                float4 m = red[f4];
                atomicAdd(&ge[g * IN_FEATS + f4 * 4 + 0], m.x);
                atomicAdd(&ge[g * IN_FEATS + f4 * 4 + 1], m.y);
                atomicAdd(&ge[g * IN_FEATS + f4 * 4 + 2], m.z);
                atomicAdd(&ge[g * IN_FEATS + f4 * 4 + 3], m.w);
            }
            __syncthreads();
        }
    }
    __syncthreads();

    // y0 pass: one row per thread, reads hit L1/L2 (chunk just streamed above)
    {
        int row = c0 + tid;
        if (row < c1) {
            const float4* r4 = reinterpret_cast<const float4*>(nf + (long long)row * IN_FEATS);
            float a0 = 0.f, a1 = 0.f;
            #pragma unroll
            for (int v = 0; v < IN_FEATS / 4; v++) {
                float4 q = r4[v];
                float2 m0 = Ms[4 * v + 0], m1 = Ms[4 * v + 1];
                float2 m2 = Ms[4 * v + 2], m3 = Ms[4 * v + 3];
                a0 += q.x * m0.x + q.y * m1.x + q.z * m2.x + q.w * m3.x;
                a1 += q.x * m0.y + q.y * m1.y + q.z * m2.y + q.w * m3.y;
            }
            reinterpret_cast<float2*>(y0)[row] = make_float2(a0, a1);
        }
    }
}

// ---------------- K2: prediction + scan (wave-level shfl scan, 1 block) ----------------
__global__ __launch_bounds__(256) void k_pred_scan(const int* __restrict__ gcount,
                                                   int* __restrict__ gbase,
                                                   int* __restrict__ gcur, int E,
                                                   const float* __restrict__ ge,
                                                   const int* __restrict__ gstart,
                                                   const float* __restrict__ Wl,
                                                   const float* __restrict__ bl,
                                                   float* __restrict__ out) {
    int tid = threadIdx.x;
    // prediction: per-graph mean dot Wl + sigmoid
    if (tid < N_GRAPHS) {
        int g = tid;
        float cnt = (float)(gstart[g + 1] - gstart[g]);
        float inv = 1.f / fmaxf(cnt, 1.0f);
        float acc = 0.f;
        for (int k = 0; k < IN_FEATS; k++)
            acc += ge[g * IN_FEATS + k] * Wl[k];
        acc = acc * inv + bl[0];
        out[g] = 1.f / (1.f + expf(-acc));
    }
    // exclusive scan of gcount[0..NB): thread owns elems 2t,2t+1; wave shfl scan
    int c0 = gcount[2 * tid], c1 = gcount[2 * tid + 1];
    int s = c0 + c1;
    int lane = tid & 63, wv = tid >> 6;
    int v = s;
    #pragma unroll
    for (int off = 1; off < 64; off <<= 1) {
        int u = __shfl_up(v, off, 64);
        if (lane >= off) v += u;
    }
    __shared__ int wsum[4];
    if (lane == 63) wsum[wv] = v;
    __syncthreads();
    int woff = 0;
    #pragma unroll
    for (int w = 0; w < 4; w++) if (w < wv) woff += wsum[w];
    int excl = v + woff - s;
    gbase[2 * tid] = excl;         gbase[2 * tid + 1] = excl + c0;
    gcur[2 * tid]  = excl;         gcur[2 * tid + 1]  = excl + c0;
    if (tid == 0) gbase[NB] = E;
}

// ---------------- K3: partition (R6 body, ladder scan -> wave shfl scan) ----------------
// packed pair: (src << 8) | (dst - bucket_base); nb_sz<=256
__global__ __launch_bounds__(256) void k_partition(const int* __restrict__ src,
                                                   const int* __restrict__ dst,
                                                   int* __restrict__ gcur,
                                                   unsigned int* __restrict__ pairs,
                                                   int E, int nb_sz) {
    __shared__ unsigned int stage[PCH];
    __shared__ unsigned short sbk[PCH];
    __shared__ int sA[NB], ofs[NB + 1], cur[NB], rbase[NB];
    __shared__ int wsum[4];
    int tid = threadIdx.x;
    int e0 = blockIdx.x * PCH;
    int m = E - e0; if (m > PCH) m = PCH;

    for (int k = tid; k < NB; k += 256) sA[k] = 0;
    __syncthreads();
    for (int i = tid; i < m; i += 256)
        atomicAdd(&sA[dst[e0 + i] / nb_sz], 1);
    __syncthreads();

    // exclusive scan of sA[0..NB) via wave shfl (thread owns 2t, 2t+1)
    {
        int c0 = sA[2 * tid], c1 = sA[2 * tid + 1];
        int s = c0 + c1;
        int lane = tid & 63, wv = tid >> 6;
        int v = s;
        #pragma unroll
        for (int off = 1; off < 64; off <<= 1) {
            int u = __shfl_up(v, off, 64);
            if (lane >= off) v += u;
        }
        if (lane == 63) wsum[wv] = v;
        __syncthreads();
        int woff = 0;
        #pragma unroll
        for (int w = 0; w < 4; w++) if (w < wv) woff += wsum[w];
        int excl = v + woff - s;
        ofs[2 * tid] = excl;       ofs[2 * tid + 1] = excl + c0;
        cur[2 * tid] = excl;       cur[2 * tid + 1] = excl + c0;
        if (tid == 0) ofs[NB] = m;
    }
    __syncthreads();

    for (int i = tid; i < m; i += 256) {
        int d = dst[e0 + i];
        int s = src[e0 + i];
        int b = d / nb_sz;
        int p = atomicAdd(&cur[b], 1);
        stage[p] = ((unsigned)s << 8) | (unsigned)(d - b * nb_sz);
        sbk[p] = (unsigned short)b;
    }
    __syncthreads();
    for (int k = tid; k < NB; k += 256) {
        int cnt = ofs[k + 1] - ofs[k];
        rbase[k] = cnt > 0 ? atomicAdd(&gcur[k], cnt) : 0;
    }
    __syncthreads();
    for (int i = tid; i < m; i += 256) {
        int b = sbk[i];
        pairs[rbase[b] + (i - ofs[b])] = stage[i];
    }
}

// ---------------- K4: csr finalize (ladder scan -> wave shfl scan) ----------------
__global__ __launch_bounds__(256) void k_csr_local(const unsigned int* __restrict__ pairs,
                                                   const int* __restrict__ gbase,
                                                   int* __restrict__ csr,
                                                   int* __restrict__ ptr,
                                                   int N, int nb_sz) {
    int b = blockIdx.x;
    int n0 = b * nb_sz;
    if (n0 >= N) return;
    int n1 = n0 + nb_sz; if (n1 > N) n1 = N;
    int nn = n1 - n0;

    __shared__ int cnt[256], cur[256];
    __shared__ int wsum[4];
    int tid = threadIdx.x;
    cnt[tid] = 0;
    __syncthreads();
    int s = gbase[b], e = gbase[b + 1];
    for (int i = s + tid; i < e; i += 256)
        atomicAdd(&cnt[pairs[i] & 0xFFu], 1);
    __syncthreads();
    int c = cnt[tid];
    // inclusive scan of cnt via wave shfl
    int lane = tid & 63, wv = tid >> 6;
    int v = c;
    #pragma unroll
    for (int off = 1; off < 64; off <<= 1) {
        int u = __shfl_up(v, off, 64);
        if (lane >= off) v += u;
    }
    if (lane == 63) wsum[wv] = v;
    __syncthreads();
    int woff = 0;
    #pragma unroll
    for (int w = 0; w < 4; w++) if (w < wv) woff += wsum[w];
    int incl = v + woff;
    cur[tid] = incl - c;
    if (tid < nn) ptr[n0 + tid] = s + incl;   // end offset
    __syncthreads();
    for (int i = s + tid; i < e; i += 256) {
        unsigned int p = pairs[i];
        int pos = atomicAdd(&cur[p & 0xFFu], 1);
        csr[s + pos] = (int)(p >> 8);
    }
}

// ---------------- hop gathers: 8 lanes per node (R1-proven) ----------------
__global__ __launch_bounds__(256) void k_gather8(const float* __restrict__ tin,
                                                 const int* __restrict__ csr,
                                                 const int* __restrict__ ptr,
                                                 const float* __restrict__ cadd,
                                                 float* __restrict__ tout, int n) {
    int t = blockIdx.x * 256 + threadIdx.x;
    int node = t >> 3;
    int lane = t & 7;
    if (node >= n) return;
    int start = node ? ptr[node - 1] : 0;
    int end = ptr[node];
    const float2* tin2 = reinterpret_cast<const float2*>(tin);
    float a0 = 0.f, a1 = 0.f;
    int j = start + lane;
    for (; j + 8 < end; j += 16) {
        int s0 = csr[j], s1 = csr[j + 8];
        float2 v0 = tin2[s0], v1 = tin2[s1];
        a0 += v0.x + v1.x;
        a1 += v0.y + v1.y;
    }
    if (j < end) {
        float2 v = tin2[csr[j]];
        a0 += v.x; a1 += v.y;
    }
    #pragma unroll
    for (int off = 4; off > 0; off >>= 1) {
        a0 += __shfl_xor(a0, off, 64);
        a1 += __shfl_xor(a1, off, 64);
    }
    if (lane == 0) {
        float deg = (float)(end - start);
        reinterpret_cast<float2*>(tout)[node] = make_float2(a0 + deg * cadd[0], a1 + deg * cadd[1]);
    }
}

// hop 3 fused with +b3, straight into d_out
__global__ __launch_bounds__(256) void k_gather8_out(const float* __restrict__ tin,
                                                     const int* __restrict__ csr,
                                                     const int* __restrict__ ptr,
                                                     const float* __restrict__ cadd,
                                                     const float* __restrict__ b3,
                                                     float* __restrict__ out, int n) {
    int t = blockIdx.x * 256 + threadIdx.x;
    int node = t >> 3;
    int lane = t & 7;
    if (node >= n) return;
    int start = node ? ptr[node - 1] : 0;
    int end = ptr[node];
    const float2* tin2 = reinterpret_cast<const float2*>(tin);
    float a0 = 0.f, a1 = 0.f;
    int j = start + lane;
    for (; j + 8 < end; j += 16) {
        int s0 = csr[j], s1 = csr[j + 8];
        float2 v0 = tin2[s0], v1 = tin2[s1];
        a0 += v0.x + v1.x;
        a1 += v0.y + v1.y;
    }
    if (j < end) {
        float2 v = tin2[csr[j]];
        a0 += v.x; a1 += v.y;
    }
    #pragma unroll
    for (int off = 4; off > 0; off >>= 1) {
        a0 += __shfl_xor(a0, off, 64);
        a1 += __shfl_xor(a1, off, 64);
    }
    if (lane == 0) {
        float deg = (float)(end - start);
        reinterpret_cast<float2*>(out)[node] =
            make_float2(a0 + deg * cadd[0] + b3[0], a1 + deg * cadd[1] + b3[1]);
    }
}

extern "C" void kernel_launch(void* const* d_in, const int* in_sizes, int n_in,
                              void* d_out, int out_size, void* d_ws, size_t ws_size,
                              hipStream_t stream) {
    const float* nf = (const float*)d_in[0];   // node_feats f32 [N,64]
    const float* W1 = (const float*)d_in[2];   // [64,32]
    const float* b1 = (const float*)d_in[3];   // [32]
    const float* W2 = (const float*)d_in[4];   // [32,32]
    const float* b2 = (const float*)d_in[5];   // [32]
    const float* W3 = (const float*)d_in[6];   // [32,2]
    const float* b3 = (const float*)d_in[7];   // [2]
    const float* Wl = (const float*)d_in[8];   // [64,1]
    const float* bl = (const float*)d_in[9];   // [1]
    const int* src  = (const int*)d_in[10];
    const int* dst  = (const int*)d_in[11];
    const int* gids = (const int*)d_in[12];

    const int N = in_sizes[0] / IN_FEATS;     // 100000
    const int E = in_sizes[10];               // 1600000
    const int nb_sz = (N + NB - 1) / NB;      // 196 (<=256 required for packing)

    float* out = (float*)d_out;

    // workspace: y0/t [N,2] ×2 ping-pong | pairs [E] | csr [E] | ptr [N] | small
    float* yA = (float*)d_ws;                 // [N,2]
    float* yB = yA + (size_t)N * 2;           // [N,2]
    unsigned int* pairs = (unsigned int*)(yB + (size_t)N * 2); // [E]
    int* csr     = (int*)(pairs + E);         // [E]
    int* ptr     = csr + E;                   // [N]
    int* gcount  = ptr + N;                   // [NB]
    int* gbase   = gcount + NB;               // [NB+1]
    int* gcur    = gbase + NB + 1;            // [NB]
    float* Mg    = (float*)(gcur + NB);       // [64,2]
    float* cc    = Mg + IN_FEATS * 2;         // [6]
    float* ge    = cc + 8;                    // [64,64]
    int* gstart  = (int*)(ge + N_GRAPHS * IN_FEATS); // [65]
    int* done    = gstart + N_GRAPHS + 1;     // [2]

    const int TB = 256;
    int gsBlocks = (N + GCH - 1) / GCH;       // 391
    int partBlocks = (E + PCH - 1) / PCH;     // 782
    int gathBlocks = ((N * 8) + TB - 1) / TB; // 3125

    // K0: bounds + zeros + folded weights
    k_init<<<1, TB, 0, stream>>>(gids, N, gstart, ge, gcount, done,
                                 W1, b1, W2, b2, W3, Mg, cc);

    // K1: fused {gsum + y0} ∥ {hist}
    k_gsum_y0h<<<gsBlocks + HISTB, TB, 0, stream>>>(nf, gids, gstart, ge, N, gsBlocks,
                                                    Mg, yA, dst, gcount, E, nb_sz);

    // K2: prediction + scan (tiny)
    k_pred_scan<<<1, TB, 0, stream>>>(gcount, gbase, gcur, E, ge, gstart, Wl, bl, out);

    // K3..K4: CSR build
    k_partition<<<partBlocks, TB, 0, stream>>>(src, dst, gcur, pairs, E, nb_sz);
    k_csr_local<<<NB, TB, 0, stream>>>(pairs, gbase, csr, ptr, N, nb_sz);

    // K5..K7: three 2-wide hops, 8 lanes/node edge-parallel
    k_gather8<<<gathBlocks, TB, 0, stream>>>(yA, csr, ptr, cc + 0, yB, N);       // hop1
    k_gather8<<<gathBlocks, TB, 0, stream>>>(yB, csr, ptr, cc + 2, yA, N);       // hop2 (+c1)
    k_gather8_out<<<gathBlocks, TB, 0, stream>>>(yA, csr, ptr, cc + 4, b3,
                                                 out + N_GRAPHS, N);             // hop3 (+c2,+b3)
}